// Round 3
// baseline (1065.931 us; speedup 1.0000x reference)
//
#include <hip/hip_runtime.h>

#define NN 200000
#define NE 6400000
#define FIN 512
#define HID 16
#define NC 7
#define NB 782        // ceil(NN/256) (node blocks; also bucket count, 256 nodes/bucket)
#define K  782        // buckets: bucket = dst >> 8
#define CHC 8192      // edges per bcount block
#define EBC 782       // NE / CHC (rounded up)
#define CHF 16384     // edges per bfill block
#define EBF 391       // NE / CHF (rounded up)
#define KC 32

// ============ kernel 1: fused bucket-count (blocks 0..781) + gemm1 (blocks 782..1563) ============
// bcount: LDS histogram of dst>>8, one global atomic per nonzero (block,bucket).
// gemm1:  h1 = x @ W1 (raw, no dinv — prescale happens in k_bcsr tail).

__global__ __launch_bounds__(256) void k_mix(const int* __restrict__ dst, int* __restrict__ bucket_total,
                                             const float* __restrict__ x, const float* __restrict__ W1,
                                             float* __restrict__ h1) {
    __shared__ float smem[KC][257];   // gemm tile; aliased as int hist[K] by bcount branch
    const int tid = threadIdx.x;

    if (blockIdx.x < EBC) {
        // ---- bucket count ----
        int* hist = (int*)smem;
        long e0 = (long)blockIdx.x * CHC;
        int cnt = (int)min((long)CHC, (long)NE - e0);
        for (int i = tid; i < K; i += 256) hist[i] = 0;
        __syncthreads();
        for (int i = tid; i < cnt; i += 256) atomicAdd(&hist[dst[e0 + i] >> 8], 1);
        __syncthreads();
        for (int b = tid; b < K; b += 256) {
            int h = hist[b];
            if (h) atomicAdd(&bucket_total[b], h);
        }
        return;
    }

    // ---- gemm1 ----
    const int row0 = (blockIdx.x - EBC) * 256;
    const int row = row0 + tid;
    float acc[HID];
    #pragma unroll
    for (int c = 0; c < HID; ++c) acc[c] = 0.f;

    for (int k0 = 0; k0 < FIN; k0 += KC) {
        __syncthreads();
        #pragma unroll
        for (int j = 0; j < 8; ++j) {
            int f = tid + 256 * j;
            int r = f >> 3;
            int kq = f & 7;
            int gr = row0 + r;
            float4 v = make_float4(0.f, 0.f, 0.f, 0.f);
            if (gr < NN) v = *(const float4*)(x + (size_t)gr * FIN + k0 + kq * 4);
            smem[kq * 4 + 0][r] = v.x;
            smem[kq * 4 + 1][r] = v.y;
            smem[kq * 4 + 2][r] = v.z;
            smem[kq * 4 + 3][r] = v.w;
        }
        __syncthreads();
        #pragma unroll 4
        for (int k = 0; k < KC; ++k) {
            float xv = smem[k][tid];
            const float4* w = (const float4*)(W1 + (size_t)(k0 + k) * HID);
            float4 w0 = w[0], w1 = w[1], w2 = w[2], w3 = w[3];
            acc[0]  = fmaf(xv, w0.x, acc[0]);  acc[1]  = fmaf(xv, w0.y, acc[1]);
            acc[2]  = fmaf(xv, w0.z, acc[2]);  acc[3]  = fmaf(xv, w0.w, acc[3]);
            acc[4]  = fmaf(xv, w1.x, acc[4]);  acc[5]  = fmaf(xv, w1.y, acc[5]);
            acc[6]  = fmaf(xv, w1.z, acc[6]);  acc[7]  = fmaf(xv, w1.w, acc[7]);
            acc[8]  = fmaf(xv, w2.x, acc[8]);  acc[9]  = fmaf(xv, w2.y, acc[9]);
            acc[10] = fmaf(xv, w2.z, acc[10]); acc[11] = fmaf(xv, w2.w, acc[11]);
            acc[12] = fmaf(xv, w3.x, acc[12]); acc[13] = fmaf(xv, w3.y, acc[13]);
            acc[14] = fmaf(xv, w3.z, acc[14]); acc[15] = fmaf(xv, w3.w, acc[15]);
        }
    }
    if (row < NN) {
        float4* o = (float4*)(h1 + (size_t)row * HID);
        o[0] = make_float4(acc[0], acc[1], acc[2], acc[3]);
        o[1] = make_float4(acc[4], acc[5], acc[6], acc[7]);
        o[2] = make_float4(acc[8], acc[9], acc[10], acc[11]);
        o[3] = make_float4(acc[12], acc[13], acc[14], acc[15]);
    }
}

// ============ bucket base scan ============

__global__ __launch_bounds__(1024) void k_bscan(const int* __restrict__ bucket_total,
                                                int* __restrict__ bucket_base, int* __restrict__ bucket_cursor) {
    __shared__ int tmp[1024];
    int i = threadIdx.x;
    int v = (i < K) ? bucket_total[i] : 0;
    tmp[i] = v;
    __syncthreads();
    #pragma unroll
    for (int off = 1; off < 1024; off <<= 1) {
        int t = (i >= off) ? tmp[i - off] : 0;
        __syncthreads();
        tmp[i] += t;
        __syncthreads();
    }
    if (i < K) {
        int base = tmp[i] - v;
        bucket_base[i] = base;
        bucket_cursor[i] = base;
    }
    if (i == K - 1) bucket_base[K] = tmp[i];
}

// ============ bucket fill: 2-pass LDS hist, direct global scatter (no stage, no scan) ============

__global__ __launch_bounds__(256) void k_bfill(const int* __restrict__ src, const int* __restrict__ dst,
                                               int* __restrict__ bucket_cursor, unsigned int* __restrict__ bwords) {
    __shared__ int hist[K];
    __shared__ int gst[K];
    int tid = threadIdx.x;
    long e0 = (long)blockIdx.x * CHF;
    int cnt = (int)min((long)CHF, (long)NE - e0);

    for (int i = tid; i < K; i += 256) hist[i] = 0;
    __syncthreads();
    for (int i = tid; i < cnt; i += 256) atomicAdd(&hist[dst[e0 + i] >> 8], 1);
    __syncthreads();
    for (int b = tid; b < K; b += 256) {
        int h = hist[b];
        gst[b] = h ? atomicAdd(&bucket_cursor[b], h) : 0;
    }
    __syncthreads();
    for (int i = tid; i < K; i += 256) hist[i] = 0;
    __syncthreads();
    for (int i = tid; i < cnt; i += 256) {
        int d = dst[e0 + i];
        int sv = src[e0 + i];
        int bin = d >> 8;
        int r = atomicAdd(&hist[bin], 1);
        bwords[gst[bin] + r] = ((unsigned int)(d & 255) << 24) | (unsigned int)sv;  // src < 2^24
    }
}

// ============ per-bucket CSR + degree + dinv + h1 prescale ============
// one block per bucket (256 nodes, ~8.2K edges); scatter stays in a 32KB L2 window.

__global__ __launch_bounds__(256) void k_bcsr(const unsigned int* __restrict__ bwords,
                                              const int* __restrict__ bucket_base,
                                              const float* __restrict__ h1,
                                              int* __restrict__ csr_src, int* __restrict__ starts,
                                              int* __restrict__ count, float* __restrict__ dinv,
                                              float* __restrict__ h1s) {
    __shared__ int cnt[256];
    __shared__ int st[256];
    int b = blockIdx.x;
    int tid = threadIdx.x;
    int n0 = b << 8;
    int n = n0 + tid;
    int p0 = bucket_base[b];
    int p1 = bucket_base[b + 1];

    // issue h1 row loads early (consumed after the histogram/scan)
    float4 r0, r1, r2, r3;
    if (n < NN) {
        const float4* q = (const float4*)(h1 + (size_t)n * HID);
        r0 = q[0]; r1 = q[1]; r2 = q[2]; r3 = q[3];
    }

    cnt[tid] = 0;
    __syncthreads();
    for (int i = p0 + tid; i < p1; i += 256) {
        unsigned int w = bwords[i];
        atomicAdd(&cnt[w >> 24], 1);
    }
    __syncthreads();
    int v = cnt[tid];
    st[tid] = v;
    __syncthreads();
    #pragma unroll
    for (int off = 1; off < 256; off <<= 1) {
        int t = (tid >= off) ? st[tid - off] : 0;
        __syncthreads();
        st[tid] += t;
        __syncthreads();
    }
    int myst = st[tid] - v;   // local exclusive prefix
    float dv = rsqrtf((float)(v + 1));
    if (n < NN) {
        starts[n] = p0 + myst;
        count[n] = v;
        dinv[n] = dv;
        float4* o = (float4*)(h1s + (size_t)n * HID);
        o[0] = make_float4(r0.x * dv, r0.y * dv, r0.z * dv, r0.w * dv);
        o[1] = make_float4(r1.x * dv, r1.y * dv, r1.z * dv, r1.w * dv);
        o[2] = make_float4(r2.x * dv, r2.y * dv, r2.z * dv, r2.w * dv);
        o[3] = make_float4(r3.x * dv, r3.y * dv, r3.z * dv, r3.w * dv);
    }
    __syncthreads();
    st[tid] = myst;
    cnt[tid] = 0;
    __syncthreads();
    for (int i = p0 + tid; i < p1; i += 256) {
        unsigned int w = bwords[i];
        int loc = w >> 24;
        int r = atomicAdd(&cnt[loc], 1);
        csr_src[p0 + st[loc] + r] = (int)(w & 0xFFFFFFu);
    }
}

// ============ fused agg1 + bias + relu + @W2 + prescale ============

__device__ __forceinline__ void add16(float* acc, const float* p) {
    const float4* q = (const float4*)p;
    float4 a = q[0], b = q[1], c = q[2], d = q[3];
    acc[0] += a.x;  acc[1] += a.y;  acc[2] += a.z;  acc[3] += a.w;
    acc[4] += b.x;  acc[5] += b.y;  acc[6] += b.z;  acc[7] += b.w;
    acc[8] += c.x;  acc[9] += c.y;  acc[10] += c.z; acc[11] += c.w;
    acc[12] += d.x; acc[13] += d.y; acc[14] += d.z; acc[15] += d.w;
}

__global__ __launch_bounds__(256) void k_agg1(const int* __restrict__ starts, const int* __restrict__ count,
                                              const int* __restrict__ csr_src, const float* __restrict__ h1s,
                                              const float* __restrict__ dinv, const float* __restrict__ b1,
                                              const float* __restrict__ W2, float* __restrict__ h2s) {
    int n = blockIdx.x * 256 + threadIdx.x;
    if (n >= NN) return;
    float acc[HID];
    {
        const float4* q = (const float4*)(h1s + (size_t)n * HID);   // self-loop term
        float4 a = q[0], b = q[1], c = q[2], d = q[3];
        acc[0] = a.x;  acc[1] = a.y;  acc[2] = a.z;  acc[3] = a.w;
        acc[4] = b.x;  acc[5] = b.y;  acc[6] = b.z;  acc[7] = b.w;
        acc[8] = c.x;  acc[9] = c.y;  acc[10] = c.z; acc[11] = c.w;
        acc[12] = d.x; acc[13] = d.y; acc[14] = d.z; acc[15] = d.w;
    }
    int beg = starts[n];
    int end = beg + count[n];
    int i = beg;
    for (; i + 3 < end; i += 4) {
        int s0 = csr_src[i], s1 = csr_src[i + 1], s2 = csr_src[i + 2], s3 = csr_src[i + 3];
        add16(acc, h1s + (size_t)s0 * HID);
        add16(acc, h1s + (size_t)s1 * HID);
        add16(acc, h1s + (size_t)s2 * HID);
        add16(acc, h1s + (size_t)s3 * HID);
    }
    for (; i < end; ++i) add16(acc, h1s + (size_t)csr_src[i] * HID);

    float dv = dinv[n];
    float h[HID];
    #pragma unroll
    for (int c = 0; c < HID; ++c) h[c] = fmaxf(fmaf(dv, acc[c], b1[c]), 0.f);
    float z[8];
    #pragma unroll
    for (int j = 0; j < NC; ++j) {
        float t = 0.f;
        #pragma unroll
        for (int c = 0; c < HID; ++c) t = fmaf(h[c], W2[c * NC + j], t);
        z[j] = t * dv;
    }
    z[7] = 0.f;
    float4* o = (float4*)(h2s + (size_t)n * 8);
    o[0] = make_float4(z[0], z[1], z[2], z[3]);
    o[1] = make_float4(z[4], z[5], z[6], z[7]);
}

// ============ fused agg2 + bias -> out ============

__global__ __launch_bounds__(256) void k_agg2(const int* __restrict__ starts, const int* __restrict__ count,
                                              const int* __restrict__ csr_src, const float* __restrict__ h2s,
                                              const float* __restrict__ dinv, const float* __restrict__ b2,
                                              float* __restrict__ out) {
    int n = blockIdx.x * 256 + threadIdx.x;
    if (n >= NN) return;
    float acc[8];
    {
        const float4* q = (const float4*)(h2s + (size_t)n * 8);     // self-loop term
        float4 a = q[0], b = q[1];
        acc[0] = a.x; acc[1] = a.y; acc[2] = a.z; acc[3] = a.w;
        acc[4] = b.x; acc[5] = b.y; acc[6] = b.z; acc[7] = b.w;
    }
    int beg = starts[n];
    int end = beg + count[n];
    int i = beg;
    for (; i + 3 < end; i += 4) {
        int s0 = csr_src[i], s1 = csr_src[i + 1], s2 = csr_src[i + 2], s3 = csr_src[i + 3];
        const float4 *p0 = (const float4*)(h2s + (size_t)s0 * 8), *p1 = (const float4*)(h2s + (size_t)s1 * 8);
        const float4 *p2 = (const float4*)(h2s + (size_t)s2 * 8), *p3 = (const float4*)(h2s + (size_t)s3 * 8);
        float4 a0 = p0[0], b0 = p0[1], a1 = p1[0], b1 = p1[1];
        float4 a2 = p2[0], b2v = p2[1], a3 = p3[0], b3 = p3[1];
        acc[0] += a0.x + a1.x + a2.x + a3.x;
        acc[1] += a0.y + a1.y + a2.y + a3.y;
        acc[2] += a0.z + a1.z + a2.z + a3.z;
        acc[3] += a0.w + a1.w + a2.w + a3.w;
        acc[4] += b0.x + b1.x + b2v.x + b3.x;
        acc[5] += b0.y + b1.y + b2v.y + b3.y;
        acc[6] += b0.z + b1.z + b2v.z + b3.z;
    }
    for (; i < end; ++i) {
        const float4* p = (const float4*)(h2s + (size_t)csr_src[i] * 8);
        float4 a = p[0], b = p[1];
        acc[0] += a.x; acc[1] += a.y; acc[2] += a.z; acc[3] += a.w;
        acc[4] += b.x; acc[5] += b.y; acc[6] += b.z;
    }
    float dv = dinv[n];
    #pragma unroll
    for (int j = 0; j < NC; ++j) out[(size_t)n * NC + j] = fmaf(dv, acc[j], b2[j]);
}

// ============ launch ============

extern "C" void kernel_launch(void* const* d_in, const int* in_sizes, int n_in,
                              void* d_out, int out_size, void* d_ws, size_t ws_size,
                              hipStream_t stream) {
    const float* x  = (const float*)d_in[0];
    const int*   ei = (const int*)d_in[1];
    const float* W1 = (const float*)d_in[2];
    const float* b1 = (const float*)d_in[3];
    const float* W2 = (const float*)d_in[4];
    const float* b2 = (const float*)d_in[5];
    const int* src = ei;
    const int* dst = ei + NE;
    float* out = (float*)d_out;

    char* ws = (char*)d_ws;
    size_t o = 0;
    auto alloc = [&](size_t bytes) {
        char* p = ws + o;
        o = (o + bytes + 255) & ~(size_t)255;
        return p;
    };
    int*   bucket_total  = (int*)alloc((size_t)(K + 1) * 4);
    int*   bucket_base   = (int*)alloc((size_t)(K + 1) * 4);
    int*   bucket_cursor = (int*)alloc((size_t)(K + 1) * 4);
    unsigned int* bwords = (unsigned int*)alloc((size_t)NE * 4);
    int*   csr_src  = (int*)alloc((size_t)NE * 4);
    int*   starts   = (int*)alloc((size_t)NN * 4);
    int*   count    = (int*)alloc((size_t)NN * 4);
    float* dinv     = (float*)alloc((size_t)NN * 4);
    float* h1       = (float*)alloc((size_t)NN * HID * 4);
    float* h1s      = (float*)alloc((size_t)NN * HID * 4);
    float* h2s      = (float*)alloc((size_t)NN * 8 * 4);

    hipMemsetAsync(bucket_total, 0, (size_t)(K + 1) * 4, stream);
    k_mix  <<<EBC + NB, 256, 0, stream>>>(dst, bucket_total, x, W1, h1);
    k_bscan<<<1, 1024, 0, stream>>>(bucket_total, bucket_base, bucket_cursor);
    k_bfill<<<EBF, 256, 0, stream>>>(src, dst, bucket_cursor, bwords);
    k_bcsr <<<K, 256, 0, stream>>>(bwords, bucket_base, h1, csr_src, starts, count, dinv, h1s);
    k_agg1 <<<NB, 256, 0, stream>>>(starts, count, csr_src, h1s, dinv, b1, W2, h2s);
    k_agg2 <<<NB, 256, 0, stream>>>(starts, count, csr_src, h2s, dinv, b2, out);
}